// Round 8
// baseline (180.932 us; speedup 1.0000x reference)
//
#include <hip/hip_runtime.h>

#define NVOX 120000
#define KVOL 27
#define CH 64
#define TOTAL (NVOX * CH)
#define NF4 (TOTAL / 4)
#define EPSV 1e-5f

typedef __attribute__((ext_vector_type(8))) short bf16x8;
typedef __attribute__((ext_vector_type(8))) unsigned short u16x8;
typedef __attribute__((ext_vector_type(4))) float f32x4;
typedef __attribute__((address_space(1))) const void gconst_t;
typedef __attribute__((address_space(3))) void lvoid_t;

__device__ __forceinline__ unsigned short f2bf(float f) {
    unsigned int u = __builtin_bit_cast(unsigned int, f);
    u += 0x7FFFu + ((u >> 16) & 1u);          // RNE
    return (unsigned short)(u >> 16);
}

// ---- prep: weight shuffle + feats->bf16 + sentinel row + stats zero --------
// weight fp32 [k][c][d] -> bf16 MFMA-fragment order:
//   wtf[((k*8 + grp)*64 + lane)*8 + j], grp=(d>>4)*2+(c>>5),
//   lane=((c&31)>>3)*16+(d&15), j=c&7   (validated rounds 4-8, unchanged)
// feats fp32 [N][64] -> bf16 [N+1][64], row N = zeros (sentinel for idx<0)
#define WBLK 432                 // 27*64*64 / 256
#define FBLK 3750                // 7,680,000 / (256*8)
__global__ void prep(const float* __restrict__ w, const float* __restrict__ feats,
                     unsigned short* __restrict__ wtf, unsigned short* __restrict__ fb,
                     float* __restrict__ stats) {
    const int b = blockIdx.x;
    const int tid = threadIdx.x;
    if (b < WBLK) {
        const int t = b * 256 + tid;           // t = k*4096 + c*64 + d (coalesced read)
        const int d = t & 63, c = (t >> 6) & 63, k = t >> 12;
        const int grp = (d >> 4) * 2 + (c >> 5);
        const int l = ((c & 31) >> 3) * 16 + (d & 15);
        const int j = c & 7;
        wtf[(((size_t)k * 8 + grp) * 64 + l) * 8 + j] = f2bf(w[t]);
        if (b == 0 && tid < 128) stats[tid] = 0.f;
        if (b == 1 && tid < 8) ((u16x8*)fb)[(size_t)NVOX * 8 + tid] = (u16x8)0;
    } else {
        const int t = (b - WBLK) * 256 + tid;  // handles 8 consecutive floats
        const float4* src = (const float4*)feats + (size_t)t * 2;
        const float4 p0 = src[0];
        const float4 p1 = src[1];
        u16x8 v = {f2bf(p0.x), f2bf(p0.y), f2bf(p0.z), f2bf(p0.w),
                   f2bf(p1.x), f2bf(p1.y), f2bf(p1.z), f2bf(p1.w)};
        ((u16x8*)fb)[t] = v;
    }
}

// ---- conv: 16 vox/wave, 1875 blocks, plain-barrier phases (race-free) ------
// Occupancy is the wall (r2/r4: ~8-9 waves/CU, MFMA+VALU+HBM all idle).
// 1875 blocks x 4 waves x 16 vox (1875*64 = 120000 exactly -> no tail,
// uniform control flow). LDS 16.9 KB -> 9 blocks/CU; VGPR ~60 -> grid-limited
// ~29 resident waves/CU (3x r2). r5/r6 failed with hand-counted vmcnt ledgers
// (race signatures); this round uses ONLY __syncthreads() (compiler-emitted
// vmcnt(0) lgkmcnt(0) + s_barrier, m97-style): stage fully drained before any
// wave crosses, all ds_reads complete at each barrier, gathers issued one
// phase ahead simply complete early. No inline asm anywhere. Latency hiding
// comes from multi-block overlap per CU, not intra-wave pipelining.
// Per phase k: stage slice k+1 (8 KB block-wide via global_load_lds into
// double buffer), gather slice k+1 A-frags (branchless sentinel), load slice
// k+2 indices, compute slice k (8 ds_read_b128 + 8 MFMA, wave-uniform skip).
__launch_bounds__(256, 4)
__global__ void conv_mfma(const unsigned short* __restrict__ FB,
                          const unsigned short* __restrict__ WtF,
                          const int* __restrict__ nbr,
                          float* __restrict__ out,
                          float* __restrict__ stats) {
    __shared__ unsigned short wlds[2][4096];   // 2 x 8 KB weight slice buffers
    __shared__ float lstats[128];
    const int tid = threadIdx.x;
    const int lane = tid & 63;
    const int wv = tid >> 6;                   // 0..3
    const int m = lane & 15;
    const int q = lane >> 4;
    const int v0 = blockIdx.x * 64 + wv * 16;
    const int r = v0 + m;                      // always valid (no tail)

    f32x4 acc[4];
#pragma unroll
    for (int nt = 0; nt < 4; ++nt)
        acc[nt] = (f32x4){0.f, 0.f, 0.f, 0.f};
    if (tid < 128) lstats[tid] = 0.f;

    const bf16x8* fbv = (const bf16x8*)FB;     // 8 x bf16x8 per 128B row

    // ---- prologue: stage slice 0, gather slice 0, idx slice 1 ----
    {
        const unsigned short* g = WtF + wv * 1024 + lane * 8;   // this wave's 2KB
        __builtin_amdgcn_global_load_lds((gconst_t*)g,         (lvoid_t*)&wlds[0][wv * 1024],       16, 0, 0);
        __builtin_amdgcn_global_load_lds((gconst_t*)(g + 512), (lvoid_t*)&wlds[0][wv * 1024 + 512], 16, 0, 0);
    }
    bf16x8 a0, a1;
    bool msk;
    int idxn;
    {
        const int ii = nbr[r];
        msk = (__ballot(ii >= 0) != 0ULL);
        const bf16x8* row = fbv + (size_t)(ii < 0 ? NVOX : ii) * 8;
        a0 = row[q];
        a1 = row[q + 4];
        idxn = nbr[NVOX + r];
    }
    __syncthreads();                           // stage 0 + lstats init complete

    for (int k = 0; k < KVOL; ++k) {
        const int nb = k & 1;
        // 1. stage slice k+1 into the other buffer
        if (k + 1 < KVOL) {
            const unsigned short* g = WtF + (size_t)(k + 1) * 4096 + wv * 1024 + lane * 8;
            __builtin_amdgcn_global_load_lds((gconst_t*)g,         (lvoid_t*)&wlds[nb ^ 1][wv * 1024],       16, 0, 0);
            __builtin_amdgcn_global_load_lds((gconst_t*)(g + 512), (lvoid_t*)&wlds[nb ^ 1][wv * 1024 + 512], 16, 0, 0);
        }

        // 2. branchless gather slice k+1 (consumed next iteration)
        const bool mn = (__ballot(idxn >= 0) != 0ULL);
        const bf16x8* rw = fbv + (size_t)(idxn < 0 ? NVOX : idxn) * 8;
        const bf16x8 an0 = rw[q];
        const bf16x8 an1 = rw[q + 4];

        // 3. idx load for slice k+2
        int idxf = -1;
        if (k + 2 < KVOL) idxf = nbr[(size_t)(k + 2) * NVOX + r];

        // 4. compute slice k from wlds[nb] (wave-uniform skip)
        if (msk) {
            const unsigned short* wk = &wlds[nb][lane * 8];
#pragma unroll
            for (int nt = 0; nt < 4; ++nt) {
                const bf16x8 b0 = *(const bf16x8*)(wk + (nt * 2    ) * 512);
                const bf16x8 b1 = *(const bf16x8*)(wk + (nt * 2 + 1) * 512);
                acc[nt] = __builtin_amdgcn_mfma_f32_16x16x32_bf16(a0, b0, acc[nt], 0, 0, 0);
                acc[nt] = __builtin_amdgcn_mfma_f32_16x16x32_bf16(a1, b1, acc[nt], 0, 0, 0);
            }
        }

        // 5. full drain + barrier (stage k+1 ready; all LDS reads done)
        __syncthreads();

        // 6. shift pipeline
        a0 = an0; a1 = an1; msk = mn; idxn = idxf;
    }

    // ---- epilogue: stores + block-reduced BN statistics ----
    // D layout: col = m (channel nt*16+m), row = q*4 + rr (voxel within tile)
    {
        float* ob = out + (size_t)(v0 + q * 4) * CH + m;
#pragma unroll
        for (int nt = 0; nt < 4; ++nt)
#pragma unroll
            for (int rr = 0; rr < 4; ++rr)
                ob[(size_t)rr * CH + nt * 16] = acc[nt][rr];
    }

#pragma unroll
    for (int nt = 0; nt < 4; ++nt) {
        float s = 0.f, s2 = 0.f;
#pragma unroll
        for (int rr = 0; rr < 4; ++rr) {
            const float x = acc[nt][rr];
            s += x;
            s2 = fmaf(x, x, s2);
        }
        s  += __shfl_xor(s, 16);  s  += __shfl_xor(s, 32);
        s2 += __shfl_xor(s2, 16); s2 += __shfl_xor(s2, 32);
        if (lane < 16) {
            atomicAdd(&lstats[nt * 16 + m], s);
            atomicAdd(&lstats[64 + nt * 16 + m], s2);
        }
    }
    __syncthreads();
    if (tid < 128) atomicAdd(&stats[tid], lstats[tid]);
}

// ---- bn_relu: grid-stride with inline finalize -----------------------------
__launch_bounds__(256)
__global__ void bn_relu(float* __restrict__ out, const float* __restrict__ stats,
                        const float* __restrict__ gamma, const float* __restrict__ beta) {
    __shared__ float sb[128];
    const int tid = threadIdx.x;
    if (tid < 64) {
        const float inv_n = 1.0f / (float)NVOX;
        const float mean = stats[tid] * inv_n;
        const float var = stats[64 + tid] * inv_n - mean * mean;
        const float sc = gamma[tid] * rsqrtf(var + EPSV);
        sb[tid] = sc;
        sb[64 + tid] = beta[tid] - mean * sc;
    }
    __syncthreads();
    float4* o4 = (float4*)out;
    for (int e = blockIdx.x * 256 + tid; e < NF4; e += 960 * 256) {
        float4 x = o4[e];
        const int cb = (e & 15) * 4;
        x.x = fmaxf(fmaf(x.x, sb[cb + 0], sb[64 + cb + 0]), 0.f);
        x.y = fmaxf(fmaf(x.y, sb[cb + 1], sb[64 + cb + 1]), 0.f);
        x.z = fmaxf(fmaf(x.z, sb[cb + 2], sb[64 + cb + 2]), 0.f);
        x.w = fmaxf(fmaf(x.w, sb[cb + 3], sb[64 + cb + 3]), 0.f);
        o4[e] = x;
    }
}

extern "C" void kernel_launch(void* const* d_in, const int* in_sizes, int n_in,
                              void* d_out, int out_size, void* d_ws, size_t ws_size,
                              hipStream_t stream) {
    const float* feats  = (const float*)d_in[0];   // [N, 64]
    const float* weight = (const float*)d_in[1];   // [27, 64, 64]
    const float* gamma  = (const float*)d_in[2];   // [64]
    const float* beta   = (const float*)d_in[3];   // [64]
    const int*   nbr    = (const int*)d_in[4];     // [27, N]
    float* out = (float*)d_out;                    // [N, 64]

    // ws layout: [0,512) stats; [512, 512+221184) WtF bf16 frag-order;
    //            [221696, 221696+15360128) featsB bf16 [N+1][64] (sentinel row N)
    float* stats = (float*)d_ws;
    unsigned short* WtF = (unsigned short*)((char*)d_ws + 512);
    unsigned short* FB  = (unsigned short*)((char*)d_ws + 512 + 221184);

    prep<<<WBLK + FBLK, 256, 0, stream>>>(weight, feats, WtF, FB, stats);
    conv_mfma<<<NVOX / 64, 256, 0, stream>>>(FB, WtF, nbr, out, stats);
    bn_relu<<<960, 256, 0, stream>>>(out, stats, gamma, beta);
}

// Round 10
// 154.248 us; speedup vs baseline: 1.1730x; 1.1730x over previous
//
#include <hip/hip_runtime.h>

#define NVOX 120000
#define KVOL 27
#define CH 64
#define TOTAL (NVOX * CH)
#define NF4 (TOTAL / 4)
#define EPSV 1e-5f

typedef __attribute__((ext_vector_type(8))) short bf16x8;
typedef __attribute__((ext_vector_type(8))) unsigned short u16x8;
typedef __attribute__((ext_vector_type(4))) float f32x4;
typedef __attribute__((address_space(1))) const void gconst_t;
typedef __attribute__((address_space(3))) void lvoid_t;

__device__ __forceinline__ unsigned short f2bf(float f) {
    unsigned int u = __builtin_bit_cast(unsigned int, f);
    u += 0x7FFFu + ((u >> 16) & 1u);          // RNE
    return (unsigned short)(u >> 16);
}

// ---- prep: weight shuffle (LDS-permuted, coalesced I/O) + feats->bf16 ------
// weight fp32 [k][c][d] -> bf16 MFMA-fragment order (validated layout):
//   wtf[((k*8+grp)*64+l)*8+j], grp=(d>>4)*2+(c>>5), l=((c&31)>>3)*16+(d&15),
//   j=c&7.  Blocks 0..26: one k-slice each — coalesced float4 reads, in-LDS
//   permute (scattered ds_write_b16 is cheap), coalesced u16x8 writes.
//   Blocks 27..3776: feats fp32 [N][64] -> bf16 [N+1][64] (8 bf16/thread,
//   3750*256*8 = 7,680,000 exactly); row N = zeros (sentinel for idx<0).
#define PGRID (27 + 3750)
__global__ void prep(const float* __restrict__ w, const float* __restrict__ feats,
                     unsigned short* __restrict__ wtf, unsigned short* __restrict__ fb,
                     float* __restrict__ stats) {
    __shared__ unsigned short ls[4096];
    const int b = blockIdx.x;
    const int tid = threadIdx.x;
    if (b < KVOL) {
        const int k = b;
        float4 v[4];
        const float4* src = (const float4*)(w + (size_t)k * 4096 + tid * 16);
#pragma unroll
        for (int i = 0; i < 4; ++i) v[i] = src[i];
#pragma unroll
        for (int e = 0; e < 16; ++e) {                 // e compile-time: no scratch
            const int t = tid * 16 + e;
            const int d = t & 63, c = t >> 6;
            const int grp = (d >> 4) * 2 + (c >> 5);
            const int l = ((c & 31) >> 3) * 16 + (d & 15);
            const int j = c & 7;
            ls[(grp * 64 + l) * 8 + j] = f2bf(((const float*)v)[e]);
        }
        __syncthreads();
        u16x8* dst = (u16x8*)(wtf + (size_t)k * 4096);
        const u16x8* lsv = (const u16x8*)ls;
        dst[tid * 2]     = lsv[tid * 2];
        dst[tid * 2 + 1] = lsv[tid * 2 + 1];
        if (b == 0 && tid < 128) stats[tid] = 0.f;
        if (b == 1 && tid < 8) ((u16x8*)fb)[(size_t)NVOX * 8 + tid] = (u16x8)0;
    } else {
        const int t = (b - KVOL) * 256 + tid;          // 8 consecutive floats
        const float4* src = (const float4*)feats + (size_t)t * 2;
        const float4 p0 = src[0];
        const float4 p1 = src[1];
        u16x8 v = {f2bf(p0.x), f2bf(p0.y), f2bf(p0.z), f2bf(p0.w),
                   f2bf(p1.x), f2bf(p1.y), f2bf(p1.z), f2bf(p1.w)};
        ((u16x8*)fb)[t] = v;
    }
}

// ---- conv: FROZEN round-2 kernel (58.0 us, passed twice; all restructures
// regressed or broke). 938 blocks x 4 waves x 32 vox (2 m-tiles/wave).
// Double-buffered 8 KB LDS weight stage via global_load_lds; counted
// s_waitcnt vmcnt(6) drains exactly the stage and keeps gathers(4)+idx(2)
// in flight across each s_barrier. Branchless sentinel gathers (idx<0 ->
// zero row N). All per-phase VMEM counts uniform across waves/blocks.
__launch_bounds__(256, 4)
__global__ void conv_mfma(const unsigned short* __restrict__ FB,
                          const unsigned short* __restrict__ WtF,
                          const int* __restrict__ nbr,
                          float* __restrict__ out,
                          float* __restrict__ stats) {
    __shared__ unsigned short wlds[2][4096];   // 2 x 8 KB weight slice buffers
    __shared__ float lstats[128];
    const int tid = threadIdx.x;
    const int lane = tid & 63;
    const int wv = tid >> 6;
    const int m = lane & 15;
    const int q = lane >> 4;
    const int v0 = blockIdx.x * 128 + wv * 32;
    const bool tv[2] = { v0 < NVOX, v0 + 16 < NVOX };
    const int r[2] = { v0 + m, v0 + 16 + m };

    f32x4 acc[2][4];
#pragma unroll
    for (int t = 0; t < 2; ++t)
#pragma unroll
        for (int nt = 0; nt < 4; ++nt)
            acc[t][nt] = (f32x4){0.f, 0.f, 0.f, 0.f};
    if (tid < 128) lstats[tid] = 0.f;

    const bf16x8* fbv = (const bf16x8*)FB;      // 8 x bf16x8 per 128B row

    // ---- prologue: stage slice 0, gather slice 0, idx slice 1 ----
    {
        const unsigned short* g = WtF + wv * 1024 + lane * 8;   // this wave's 2KB
        __builtin_amdgcn_global_load_lds((gconst_t*)g,         (lvoid_t*)&wlds[0][wv * 1024],       16, 0, 0);
        __builtin_amdgcn_global_load_lds((gconst_t*)(g + 512), (lvoid_t*)&wlds[0][wv * 1024 + 512], 16, 0, 0);
    }
    __builtin_amdgcn_sched_barrier(0);

    bf16x8 a[2][2];
    unsigned long long msk[2];
    int idxn[2];
#pragma unroll
    for (int t = 0; t < 2; ++t) {
        const int rr = tv[t] ? r[t] : m;        // clamped addr: load always issues
        const int i0 = nbr[rr];
        const int i = tv[t] ? i0 : -1;
        msk[t] = __ballot(i >= 0);
        const bf16x8* row = fbv + (size_t)(i < 0 ? NVOX : i) * 8;
        a[t][0] = row[q];
        a[t][1] = row[q + 4];
        const int i1 = nbr[NVOX + rr];
        idxn[t] = tv[t] ? i1 : -1;
    }
    // drain stage (oldest 2) + lstats ds_writes; keep gathers(4)+idx(2) in flight
    asm volatile("s_waitcnt vmcnt(6) lgkmcnt(0)" ::: "memory");
    __builtin_amdgcn_s_barrier();
    __builtin_amdgcn_sched_barrier(0);

    for (int k = 0; k < KVOL; ++k) {
        const int nb = k & 1;
        // 1. stage slice k+1 into wlds[nb^1] (pinned oldest in VMEM issue order)
        if (k + 1 < KVOL) {
            const unsigned short* g = WtF + (size_t)(k + 1) * 4096 + wv * 1024 + lane * 8;
            __builtin_amdgcn_global_load_lds((gconst_t*)g,         (lvoid_t*)&wlds[nb ^ 1][wv * 1024],       16, 0, 0);
            __builtin_amdgcn_global_load_lds((gconst_t*)(g + 512), (lvoid_t*)&wlds[nb ^ 1][wv * 1024 + 512], 16, 0, 0);
        }
        __builtin_amdgcn_sched_barrier(0);

        // 2. branchless gathers for slice k+1 (consumed next iteration)
        unsigned long long mn[2];
        bf16x8 an[2][2];
#pragma unroll
        for (int t = 0; t < 2; ++t) {
            mn[t] = __ballot(idxn[t] >= 0);
            const bf16x8* rw = fbv + (size_t)(idxn[t] < 0 ? NVOX : idxn[t]) * 8;
            an[t][0] = rw[q];
            an[t][1] = rw[q + 4];
        }
        // 3. idx prefetch for slice k+2 (always 2 loads: count-uniform)
        const int kk = (k + 2 < KVOL) ? (k + 2) : 0;
        const int* nbp = nbr + (size_t)kk * NVOX;
        int idxf[2];
#pragma unroll
        for (int t = 0; t < 2; ++t) {
            const int rr = tv[t] ? r[t] : m;
            const int v = nbp[rr];
            idxf[t] = (tv[t] && (k + 2 < KVOL)) ? v : -1;
        }

        // 4. weight fragments for slice k from LDS (conflict-free b128)
        const unsigned short* wk = &wlds[nb][lane * 8];
        bf16x8 bfr[8];
#pragma unroll
        for (int h = 0; h < 8; ++h)
            bfr[h] = *(const bf16x8*)(wk + h * 512);

        // 5. compute slice k (a[] gathered one iteration ago)
#pragma unroll
        for (int t = 0; t < 2; ++t) {
            if (msk[t]) {
#pragma unroll
                for (int nt = 0; nt < 4; ++nt) {
                    acc[t][nt] = __builtin_amdgcn_mfma_f32_16x16x32_bf16(a[t][0], bfr[nt * 2 + 0], acc[t][nt], 0, 0, 0);
                    acc[t][nt] = __builtin_amdgcn_mfma_f32_16x16x32_bf16(a[t][1], bfr[nt * 2 + 1], acc[t][nt], 0, 0, 0);
                }
            }
        }

        // 6. shift pipeline
#pragma unroll
        for (int t = 0; t < 2; ++t) {
            a[t][0] = an[t][0];
            a[t][1] = an[t][1];
            msk[t] = mn[t];
            idxn[t] = idxf[t];
        }

        // 7. stage(k+1) complete, gathers+idx stay in flight; swap buffers
        asm volatile("s_waitcnt vmcnt(6)" ::: "memory");
        __builtin_amdgcn_s_barrier();
        __builtin_amdgcn_sched_barrier(0);
    }

    // ---- epilogue: stores + block-reduced BN statistics ----
    // D layout: col = m (channel nt*16+m), row = q*4 + rr (voxel within tile)
#pragma unroll
    for (int t = 0; t < 2; ++t) {
        if (tv[t]) {
            float* ob = out + (size_t)(v0 + t * 16 + q * 4) * CH + m;
#pragma unroll
            for (int nt = 0; nt < 4; ++nt)
#pragma unroll
                for (int rr = 0; rr < 4; ++rr)
                    ob[(size_t)rr * CH + nt * 16] = acc[t][nt][rr];
        }
    }

#pragma unroll
    for (int nt = 0; nt < 4; ++nt) {
        float s = 0.f, s2 = 0.f;
#pragma unroll
        for (int t = 0; t < 2; ++t)
#pragma unroll
            for (int rr = 0; rr < 4; ++rr) {
                const float x = acc[t][nt][rr];   // padded tiles stay exactly 0
                s += x;
                s2 = fmaf(x, x, s2);
            }
        s  += __shfl_xor(s, 16);  s  += __shfl_xor(s, 32);
        s2 += __shfl_xor(s2, 16); s2 += __shfl_xor(s2, 32);
        if (lane < 16) {
            atomicAdd(&lstats[nt * 16 + m], s);
            atomicAdd(&lstats[64 + nt * 16 + m], s2);
        }
    }
    __syncthreads();
    if (tid < 128) atomicAdd(&stats[tid], lstats[tid]);
}

// ---- bn_relu: exact-cover grid (1875*256*4 float4 = NF4), hoisted sb -------
__launch_bounds__(256)
__global__ void bn_relu(float* __restrict__ out, const float* __restrict__ stats,
                        const float* __restrict__ gamma, const float* __restrict__ beta) {
    __shared__ float sb[128];
    const int tid = threadIdx.x;
    if (tid < 64) {
        const float inv_n = 1.0f / (float)NVOX;
        const float mean = stats[tid] * inv_n;
        const float var = stats[64 + tid] * inv_n - mean * mean;
        const float sc = gamma[tid] * rsqrtf(var + EPSV);
        sb[tid] = sc;
        sb[64 + tid] = beta[tid] - mean * sc;
    }
    __syncthreads();
    float4* o4 = (float4*)out;
    const int base = blockIdx.x * 256 + tid;       // 0..479999
    const int cb = (base & 15) * 4;                // 480000 % 16 == 0: constant
    const float s0 = sb[cb + 0], s1 = sb[cb + 1], s2 = sb[cb + 2], s3 = sb[cb + 3];
    const float b0 = sb[64 + cb + 0], b1 = sb[64 + cb + 1], b2 = sb[64 + cb + 2], b3 = sb[64 + cb + 3];
#pragma unroll
    for (int i = 0; i < 4; ++i) {
        const int e = base + i * 480000;
        float4 x = o4[e];
        x.x = fmaxf(fmaf(x.x, s0, b0), 0.f);
        x.y = fmaxf(fmaf(x.y, s1, b1), 0.f);
        x.z = fmaxf(fmaf(x.z, s2, b2), 0.f);
        x.w = fmaxf(fmaf(x.w, s3, b3), 0.f);
        o4[e] = x;
    }
}

extern "C" void kernel_launch(void* const* d_in, const int* in_sizes, int n_in,
                              void* d_out, int out_size, void* d_ws, size_t ws_size,
                              hipStream_t stream) {
    const float* feats  = (const float*)d_in[0];   // [N, 64]
    const float* weight = (const float*)d_in[1];   // [27, 64, 64]
    const float* gamma  = (const float*)d_in[2];   // [64]
    const float* beta   = (const float*)d_in[3];   // [64]
    const int*   nbr    = (const int*)d_in[4];     // [27, N]
    float* out = (float*)d_out;                    // [N, 64]

    // ws layout: [0,512) stats; [512, 512+221184) WtF bf16 frag-order;
    //            [221696, 221696+15360128) featsB bf16 [N+1][64] (sentinel row N)
    float* stats = (float*)d_ws;
    unsigned short* WtF = (unsigned short*)((char*)d_ws + 512);
    unsigned short* FB  = (unsigned short*)((char*)d_ws + 512 + 221184);

    prep<<<PGRID, 256, 0, stream>>>(weight, feats, WtF, FB, stats);
    conv_mfma<<<(NVOX + 127) / 128, 256, 0, stream>>>(FB, WtF, nbr, out, stats);
    bn_relu<<<1875, 256, 0, stream>>>(out, stats, gamma, beta);
}